// Round 2
// baseline (956.428 us; speedup 1.0000x reference)
//
#include <hip/hip_runtime.h>
#include <cstdint>
#include <cstddef>

// ---------------------------------------------------------------------------
// GATExtractPart: full-graph GAT encoder + attention pooling, f32, chunked.
// N=32768 nodes, E=131072 edges (+N self loops), B=512 graphs of L=64 nodes.
// Graphs are contiguous blocks of 64 nodes / 256 edges, so the activation
// pipeline is processed in graph-chunks sized to fit ws_size.
// ---------------------------------------------------------------------------

#define LEAKY_SLOPE 0.2f

// --- tiny precompute: we1[k][h] = sum_c We1[k,h*256+c]*ae1[h,c]; we2[k] -----
__global__ void k_pre(const float* __restrict__ We1, const float* __restrict__ ae1,
                      const float* __restrict__ We2, const float* __restrict__ ae2,
                      float* __restrict__ we1, float* __restrict__ we2) {
    int t = threadIdx.x;
    if (t < 24) {
        int k = t / 4, h = t % 4;
        float s = 0.f;
        for (int c = 0; c < 256; ++c) s += We1[k * 1024 + h * 256 + c] * ae1[h * 256 + c];
        we1[k * 4 + h] = s;
    } else if (t < 30) {
        int k = t - 24;
        float s = 0.f;
        for (int c = 0; c < 256; ++c) s += We2[k * 256 + c] * ae2[c];
        we2[k] = s;
    }
}

// --- per-dst degree + edge_attr sums (original edges only) ------------------
__global__ void k_edge_accum(const int* __restrict__ ei, const float* __restrict__ ea,
                             int* __restrict__ deg, float* __restrict__ mea, int E) {
    int e = blockIdx.x * blockDim.x + threadIdx.x;
    if (e >= E) return;
    int d = ei[E + e];
    atomicAdd(&deg[d], 1);
#pragma unroll
    for (int k = 0; k < 6; ++k) atomicAdd(&mea[d * 6 + k], ea[e * 6 + k]);
}

__global__ void k_mea_div(float* __restrict__ mea, const int* __restrict__ deg, int N) {
    int i = blockIdx.x * blockDim.x + threadIdx.x;
    if (i >= N * 6) return;
    mea[i] /= fmaxf((float)deg[i / 6], 1.f);
}

// --- exclusive scan of (deg+1) over N nodes; single block of 1024 -----------
__global__ void k_scan(const int* __restrict__ deg, int* __restrict__ off, int N) {
    __shared__ int part[1024];
    int t = threadIdx.x;
    int per = N / 1024;             // 32 for N=32768
    int base = t * per;
    int loc[32];
    int s = 0;
    for (int i = 0; i < per; ++i) { loc[i] = s; s += deg[base + i] + 1; }
    part[t] = s;
    __syncthreads();
    for (int o = 1; o < 1024; o <<= 1) {
        int v = (t >= o) ? part[t - o] : 0;
        __syncthreads();
        part[t] += v;
        __syncthreads();
    }
    int excl = (t == 0) ? 0 : part[t - 1];
    for (int i = 0; i < per; ++i) off[base + i] = excl + loc[i];
    if (t == 1023) off[N] = excl + s;
}

// --- CSR fill over full edge set (E originals + N self loops) ---------------
__global__ void k_fill(const int* __restrict__ ei, const int* __restrict__ coff,
                       int* __restrict__ fill, int* __restrict__ eid, int E, int Ef) {
    int e = blockIdx.x * blockDim.x + threadIdx.x;
    if (e >= Ef) return;
    int d = (e < E) ? ei[E + e] : (e - E);
    int pos = coff[d] + atomicAdd(&fill[d], 1);
    eid[pos] = e;
}

// --- GEMM1 (chunk): h1c[lr,1024] = x[n0+lr,55] @ W1[55,1024] ----------------
__global__ void k_gemm1(const float* __restrict__ x, const float* __restrict__ W,
                        float* __restrict__ h1c, int n0) {
    __shared__ float xs[32][56];
    __shared__ float ws[55][128];
    int tid = threadIdx.x;
    int r0 = blockIdx.y * 32, c0 = blockIdx.x * 128;
    for (int i = tid; i < 32 * 55; i += 256) {
        int r = i / 55, k = i % 55;
        xs[r][k] = x[(size_t)(n0 + r0 + r) * 55 + k];
    }
    for (int i = tid; i < 55 * 128; i += 256) {
        int k = i / 128, c = i % 128;
        ws[k][c] = W[(size_t)k * 1024 + c0 + c];
    }
    __syncthreads();
    int cg = tid % 32, ng = tid / 32;
    float acc[4][4] = {};
    for (int k = 0; k < 55; ++k) {
        float a[4], b[4];
#pragma unroll
        for (int i = 0; i < 4; ++i) a[i] = xs[ng * 4 + i][k];
#pragma unroll
        for (int j = 0; j < 4; ++j) b[j] = ws[k][cg * 4 + j];
#pragma unroll
        for (int i = 0; i < 4; ++i)
#pragma unroll
            for (int j = 0; j < 4; ++j) acc[i][j] += a[i] * b[j];
    }
#pragma unroll
    for (int i = 0; i < 4; ++i)
#pragma unroll
        for (int j = 0; j < 4; ++j)
            h1c[(size_t)(r0 + ng * 4 + i) * 1024 + c0 + cg * 4 + j] = acc[i][j];
}

// --- per-node attention scalars, layer 1 (chunk-local read, global write) ---
__global__ void k_s1(const float* __restrict__ h1c, const float* __restrict__ as1,
                     const float* __restrict__ ad1, float* __restrict__ ss,
                     float* __restrict__ sd, int n0) {
    int ln = blockIdx.x, tid = threadIdx.x;
    int n = n0 + ln;
    int h = tid >> 6, lane = tid & 63;
    const float* row = h1c + (size_t)ln * 1024 + h * 256;
    float vs = 0.f, vd = 0.f;
#pragma unroll
    for (int j = 0; j < 4; ++j) {
        int c = j * 64 + lane;
        float v = row[c];
        vs += v * as1[h * 256 + c];
        vd += v * ad1[h * 256 + c];
    }
    for (int o = 32; o; o >>= 1) { vs += __shfl_down(vs, o); vd += __shfl_down(vd, o); }
    if (lane == 0) { ss[n * 4 + h] = vs; sd[n * 4 + h] = vd; }
}

// --- per-edge attention logits, layer 1 (chunk) -----------------------------
__global__ void k_al1(const int* __restrict__ ei, const float* __restrict__ ea,
                      const float* __restrict__ mea, const float* __restrict__ ss,
                      const float* __restrict__ sd, const float* __restrict__ we1,
                      float* __restrict__ al1, int E, int e0, int ECo, int n0, int NC) {
    int idx = blockIdx.x * blockDim.x + threadIdx.x;
    if (idx >= (ECo + NC) * 4) return;
    int i = idx >> 2, h = idx & 3;
    int ge, s, d;
    const float* eap;
    if (i < ECo) {
        ge = e0 + i;
        s = ei[ge];
        d = ei[E + ge];
        eap = ea + (size_t)ge * 6;
    } else {
        int n = n0 + (i - ECo);
        ge = E + n;
        s = d = n;
        eap = mea + (size_t)n * 6;
    }
    float v = ss[s * 4 + h] + sd[d * 4 + h];
#pragma unroll
    for (int k = 0; k < 6; ++k) v += eap[k] * we1[k * 4 + h];
    al1[(size_t)ge * 4 + h] = (v > 0.f) ? v : LEAKY_SLOPE * v;
}

// --- layer1 fused: softmax over incoming edges, aggregate, +b1, LN, ReLU ----
__global__ void k_agg1(const float* __restrict__ h1c, const float* __restrict__ al1,
                       const int* __restrict__ coff, const int* __restrict__ eid,
                       const int* __restrict__ ei, const float* __restrict__ b1,
                       const float* __restrict__ g1, const float* __restrict__ be1,
                       float* __restrict__ hlnc, int E, int n0) {
    int ln = blockIdx.x, tid = threadIdx.x;
    int n = n0 + ln;
    int h = tid >> 6;
    int e0 = coff[n], e1 = coff[n + 1];
    float m = -1e30f;
    for (int p = e0; p < e1; ++p) m = fmaxf(m, al1[(size_t)eid[p] * 4 + h]);
    float ssum = 0.f;
    for (int p = e0; p < e1; ++p) ssum += expf(al1[(size_t)eid[p] * 4 + h] - m);
    float inv = 1.f / (ssum + 1e-16f);
    int c0 = tid * 4;
    float4 acc = make_float4(0.f, 0.f, 0.f, 0.f);
    for (int p = e0; p < e1; ++p) {
        int e = eid[p];
        int s = (e < E) ? ei[e] : (e - E);
        int ls = s - n0;
        float a = expf(al1[(size_t)e * 4 + h] - m) * inv;
        const float4 hv = *reinterpret_cast<const float4*>(h1c + (size_t)ls * 1024 + c0);
        acc.x += a * hv.x; acc.y += a * hv.y; acc.z += a * hv.z; acc.w += a * hv.w;
    }
    acc.x += b1[c0 + 0]; acc.y += b1[c0 + 1]; acc.z += b1[c0 + 2]; acc.w += b1[c0 + 3];
    float lsum = acc.x + acc.y + acc.z + acc.w;
    float lsq = acc.x * acc.x + acc.y * acc.y + acc.z * acc.z + acc.w * acc.w;
    for (int o = 32; o; o >>= 1) { lsum += __shfl_down(lsum, o); lsq += __shfl_down(lsq, o); }
    __shared__ float rs[4], rq[4];
    if ((tid & 63) == 0) { rs[tid >> 6] = lsum; rq[tid >> 6] = lsq; }
    __syncthreads();
    float mu = (rs[0] + rs[1] + rs[2] + rs[3]) * (1.f / 1024.f);
    float var = (rq[0] + rq[1] + rq[2] + rq[3]) * (1.f / 1024.f) - mu * mu;
    float rstd = rsqrtf(var + 1e-5f);
    float4 o4;
    o4.x = fmaxf((acc.x - mu) * rstd * g1[c0 + 0] + be1[c0 + 0], 0.f);
    o4.y = fmaxf((acc.y - mu) * rstd * g1[c0 + 1] + be1[c0 + 1], 0.f);
    o4.z = fmaxf((acc.z - mu) * rstd * g1[c0 + 2] + be1[c0 + 2], 0.f);
    o4.w = fmaxf((acc.w - mu) * rstd * g1[c0 + 3] + be1[c0 + 3], 0.f);
    *reinterpret_cast<float4*>(hlnc + (size_t)ln * 1024 + c0) = o4;
}

// --- GEMM2 (chunk): h2c[NC,256] = hlnc[NC,1024] @ W2[1024,256] --------------
__global__ void k_gemm2(const float* __restrict__ A, const float* __restrict__ W,
                        float* __restrict__ C) {
    __shared__ float as[16][65];
    __shared__ float bs[16][64];
    int tid = threadIdx.x;
    int m0 = blockIdx.y * 64, nn0 = blockIdx.x * 64;
    int mg = tid >> 4, ng = tid & 15;
    float acc[4][4] = {};
    for (int kk = 0; kk < 1024; kk += 16) {
        for (int i = tid; i < 64 * 16; i += 256) {
            int m = i >> 4, k = i & 15;
            as[k][m] = A[(size_t)(m0 + m) * 1024 + kk + k];
        }
        for (int i = tid; i < 16 * 64; i += 256) {
            int k = i >> 6, nn = i & 63;
            bs[k][nn] = W[(size_t)(kk + k) * 256 + nn0 + nn];
        }
        __syncthreads();
#pragma unroll
        for (int k = 0; k < 16; ++k) {
            float a[4], b[4];
#pragma unroll
            for (int i = 0; i < 4; ++i) a[i] = as[k][mg * 4 + i];
#pragma unroll
            for (int j = 0; j < 4; ++j) b[j] = bs[k][ng * 4 + j];
#pragma unroll
            for (int i = 0; i < 4; ++i)
#pragma unroll
                for (int j = 0; j < 4; ++j) acc[i][j] += a[i] * b[j];
        }
        __syncthreads();
    }
#pragma unroll
    for (int i = 0; i < 4; ++i)
#pragma unroll
        for (int j = 0; j < 4; ++j)
            C[(size_t)(m0 + mg * 4 + i) * 256 + nn0 + ng * 4 + j] = acc[i][j];
}

// --- per-node attention scalars, layer 2 ------------------------------------
__global__ void k_s2(const float* __restrict__ h2c, const float* __restrict__ as2,
                     const float* __restrict__ ad2, float* __restrict__ ss,
                     float* __restrict__ sd, int n0) {
    int ln = blockIdx.x, lane = threadIdx.x;   // block = 64
    const float* row = h2c + (size_t)ln * 256;
    float vs = 0.f, vd = 0.f;
#pragma unroll
    for (int j = 0; j < 4; ++j) {
        int c = j * 64 + lane;
        float v = row[c];
        vs += v * as2[c];
        vd += v * ad2[c];
    }
    for (int o = 32; o; o >>= 1) { vs += __shfl_down(vs, o); vd += __shfl_down(vd, o); }
    if (lane == 0) { ss[n0 + ln] = vs; sd[n0 + ln] = vd; }
}

__global__ void k_al2(const int* __restrict__ ei, const float* __restrict__ ea,
                      const float* __restrict__ mea, const float* __restrict__ ss,
                      const float* __restrict__ sd, const float* __restrict__ we2,
                      float* __restrict__ al2, int E, int e0, int ECo, int n0, int NC) {
    int i = blockIdx.x * blockDim.x + threadIdx.x;
    if (i >= ECo + NC) return;
    int ge, s, d;
    const float* eap;
    if (i < ECo) {
        ge = e0 + i;
        s = ei[ge];
        d = ei[E + ge];
        eap = ea + (size_t)ge * 6;
    } else {
        int n = n0 + (i - ECo);
        ge = E + n;
        s = d = n;
        eap = mea + (size_t)n * 6;
    }
    float v = ss[s] + sd[d];
#pragma unroll
    for (int k = 0; k < 6; ++k) v += eap[k] * we2[k];
    al2[ge] = (v > 0.f) ? v : LEAKY_SLOPE * v;
}

// --- layer2 fused: softmax, aggregate, +b2, LN ------------------------------
__global__ void k_agg2(const float* __restrict__ h2c, const float* __restrict__ al2,
                       const int* __restrict__ coff, const int* __restrict__ eid,
                       const int* __restrict__ ei, const float* __restrict__ b2,
                       const float* __restrict__ g2, const float* __restrict__ be2,
                       float* __restrict__ hfc, int E, int n0) {
    int ln = blockIdx.x, tid = threadIdx.x;    // 256 threads = 256 channels
    int n = n0 + ln;
    int e0 = coff[n], e1 = coff[n + 1];
    float m = -1e30f;
    for (int p = e0; p < e1; ++p) m = fmaxf(m, al2[eid[p]]);
    float ssum = 0.f;
    for (int p = e0; p < e1; ++p) ssum += expf(al2[eid[p]] - m);
    float inv = 1.f / (ssum + 1e-16f);
    float acc = 0.f;
    for (int p = e0; p < e1; ++p) {
        int e = eid[p];
        int s = (e < E) ? ei[e] : (e - E);
        float a = expf(al2[e] - m) * inv;
        acc += a * h2c[(size_t)(s - n0) * 256 + tid];
    }
    acc += b2[tid];
    float lsum = acc, lsq = acc * acc;
    for (int o = 32; o; o >>= 1) { lsum += __shfl_down(lsum, o); lsq += __shfl_down(lsq, o); }
    __shared__ float rs[4], rq[4];
    if ((tid & 63) == 0) { rs[tid >> 6] = lsum; rq[tid >> 6] = lsq; }
    __syncthreads();
    float mu = (rs[0] + rs[1] + rs[2] + rs[3]) * (1.f / 256.f);
    float var = (rq[0] + rq[1] + rq[2] + rq[3]) * (1.f / 256.f) - mu * mu;
    float rstd = rsqrtf(var + 1e-5f);
    hfc[(size_t)ln * 256 + tid] = (acc - mu) * rstd * g2[tid] + be2[tid];
}

// --- scores[n] = tanh(hfc[ln] @ Wa) . va ------------------------------------
__global__ void k_scores(const float* __restrict__ hfc, const float* __restrict__ Wa,
                         const float* __restrict__ va, float* __restrict__ scores,
                         int n0) {
    __shared__ float hs[16][256];
    int l0 = blockIdx.x * 16, tid = threadIdx.x;
    for (int i = tid; i < 16 * 256; i += 256)
        hs[i >> 8][i & 255] = hfc[(size_t)(l0 + (i >> 8)) * 256 + (i & 255)];
    __syncthreads();
    float acc[16] = {};
    int c = tid;
    for (int k = 0; k < 256; ++k) {
        float w = Wa[(size_t)k * 256 + c];
#pragma unroll
        for (int i = 0; i < 16; ++i) acc[i] += hs[i][k] * w;
    }
    float vc = va[c];
    __shared__ float red[4];
    for (int i = 0; i < 16; ++i) {
        float t = tanhf(acc[i]) * vc;
        for (int o = 32; o; o >>= 1) t += __shfl_down(t, o);
        if ((tid & 63) == 0) red[tid >> 6] = t;
        __syncthreads();
        if (tid == 0) scores[n0 + l0 + i] = red[0] + red[1] + red[2] + red[3];
        __syncthreads();
    }
}

// --- per-graph softmax + attention-weighted max-pool + embedding gather -----
__global__ void k_final(const float* __restrict__ hfc, const float* __restrict__ scores,
                        const int* __restrict__ food, const float* __restrict__ emb,
                        float* __restrict__ out, int B, int g0) {
    int b = g0 + blockIdx.x, tid = threadIdx.x;
    __shared__ float at[64];
    if (tid < 64) {
        float sc = scores[b * 64 + tid];
        float m = sc;
        for (int o = 32; o; o >>= 1) m = fmaxf(m, __shfl_xor(m, o));
        float ex = expf(sc - m);
        float s = ex;
        for (int o = 32; o; o >>= 1) s += __shfl_xor(s, o);
        float a = ex / (s + 1e-16f);
        at[tid] = a;
        out[(size_t)B * 512 + b * 64 + tid] = a;     // attn at offset 2*B*256
    }
    __syncthreads();
    int c = tid;
    float m = -1e30f;
    int lbase = blockIdx.x * 64;                     // chunk-local row base
    for (int l = 0; l < 64; ++l)
        m = fmaxf(m, hfc[(size_t)(lbase + l) * 256 + c] * at[l]);
    out[(size_t)b * 256 + c] = m;                               // drug_fea
    out[(size_t)B * 256 + b * 256 + c] = emb[(size_t)food[b] * 256 + c];  // food_fea
}

// ---------------------------------------------------------------------------
extern "C" void kernel_launch(void* const* d_in, const int* in_sizes, int n_in,
                              void* d_out, int out_size, void* d_ws, size_t ws_size,
                              hipStream_t stream) {
    const float* x   = (const float*)d_in[0];
    const float* ea  = (const float*)d_in[1];
    const int*   ei  = (const int*)d_in[2];
    const int*   food= (const int*)d_in[4];
    const float* W1  = (const float*)d_in[5];
    const float* as1 = (const float*)d_in[6];
    const float* ad1 = (const float*)d_in[7];
    const float* We1 = (const float*)d_in[8];
    const float* ae1 = (const float*)d_in[9];
    const float* b1  = (const float*)d_in[10];
    const float* g1  = (const float*)d_in[11];
    const float* be1 = (const float*)d_in[12];
    const float* W2  = (const float*)d_in[13];
    const float* as2 = (const float*)d_in[14];
    const float* ad2 = (const float*)d_in[15];
    const float* We2 = (const float*)d_in[16];
    const float* ae2 = (const float*)d_in[17];
    const float* b2  = (const float*)d_in[18];
    const float* g2  = (const float*)d_in[19];
    const float* be2 = (const float*)d_in[20];
    const float* Wa  = (const float*)d_in[21];
    const float* va  = (const float*)d_in[22];
    const float* emb = (const float*)d_in[23];
    float* out = (float*)d_out;

    const int N  = in_sizes[0] / 55;
    const int E  = in_sizes[2] / 2;
    const int B  = in_sizes[4];
    const int Ef = E + N;
    const int LPG = N / B;      // 64 nodes per graph
    const int EPG = E / B;      // 256 edges per graph

    char* w = (char*)d_ws;
    size_t off = 0;
    auto take = [&](size_t bytes) -> char* {
        char* p = w + off;
        off = (off + bytes + 255) & ~(size_t)255;
        return p;
    };
    // small full-graph buffers first (~6.5 MB)
    int*   deg  = (int*)take((size_t)N * 4);
    float* mea  = (float*)take((size_t)N * 6 * 4);
    int*   coff = (int*)take((size_t)(N + 1) * 4);
    int*   fill = (int*)take((size_t)N * 4);
    int*   eid  = (int*)take((size_t)Ef * 4);
    float* ss1  = (float*)take((size_t)N * 4 * 4);
    float* sd1  = (float*)take((size_t)N * 4 * 4);
    float* al1  = (float*)take((size_t)Ef * 4 * 4);
    float* ss2  = (float*)take((size_t)N * 4);
    float* sd2  = (float*)take((size_t)N * 4);
    float* al2  = (float*)take((size_t)Ef * 4);
    float* wbuf = (float*)take(256);          // we1[24] at wbuf, we2[6] at wbuf+32
    float* scores = (float*)take((size_t)N * 4);
    size_t smallEnd = off;

    // chunk size: largest power-of-two graph count whose activations fit ws
    int G = B;
    while (G > 1 && smallEnd + 2ull * G * LPG * 1024 * 4 + 512 > ws_size) G >>= 1;
    float* h1c  = (float*)take((size_t)G * LPG * 1024 * 4);
    float* hlnc = (float*)take((size_t)G * LPG * 1024 * 4);
    float* h2c = h1c;                              // h1c dead after k_agg1
    float* hfc = h1c + (size_t)G * LPG * 256;      // distinct from h2c range

    hipMemsetAsync(deg, 0, (size_t)N * 4, stream);
    hipMemsetAsync(mea, 0, (size_t)N * 6 * 4, stream);
    hipMemsetAsync(fill, 0, (size_t)N * 4, stream);

    k_pre<<<1, 64, 0, stream>>>(We1, ae1, We2, ae2, wbuf, wbuf + 32);
    k_edge_accum<<<(E + 255) / 256, 256, 0, stream>>>(ei, ea, deg, mea, E);
    k_mea_div<<<(N * 6 + 255) / 256, 256, 0, stream>>>(mea, deg, N);
    k_scan<<<1, 1024, 0, stream>>>(deg, coff, N);
    k_fill<<<(Ef + 255) / 256, 256, 0, stream>>>(ei, coff, fill, eid, E, Ef);

    for (int g0 = 0; g0 < B; g0 += G) {
        int Gc  = (g0 + G <= B) ? G : (B - g0);
        int n0  = g0 * LPG;
        int e0  = g0 * EPG;
        int NC  = Gc * LPG;
        int ECo = Gc * EPG;
        k_gemm1<<<dim3(8, NC / 32), 256, 0, stream>>>(x, W1, h1c, n0);
        k_s1<<<NC, 256, 0, stream>>>(h1c, as1, ad1, ss1, sd1, n0);
        k_al1<<<((ECo + NC) * 4 + 255) / 256, 256, 0, stream>>>(
            ei, ea, mea, ss1, sd1, wbuf, al1, E, e0, ECo, n0, NC);
        k_agg1<<<NC, 256, 0, stream>>>(h1c, al1, coff, eid, ei, b1, g1, be1, hlnc, E, n0);
        k_gemm2<<<dim3(4, NC / 64), 256, 0, stream>>>(hlnc, W2, h2c);
        k_s2<<<NC, 64, 0, stream>>>(h2c, as2, ad2, ss2, sd2, n0);
        k_al2<<<(ECo + NC + 255) / 256, 256, 0, stream>>>(
            ei, ea, mea, ss2, sd2, wbuf + 32, al2, E, e0, ECo, n0, NC);
        k_agg2<<<NC, 256, 0, stream>>>(h2c, al2, coff, eid, ei, b2, g2, be2, hfc, E, n0);
        k_scores<<<NC / 16, 256, 0, stream>>>(hfc, Wa, va, scores, n0);
        k_final<<<Gc, 256, 0, stream>>>(hfc, scores, food, emb, out, B, g0);
    }
}

// Round 3
// 545.084 us; speedup vs baseline: 1.7546x; 1.7546x over previous
//
#include <hip/hip_runtime.h>
#include <cstdint>
#include <cstddef>

// ---------------------------------------------------------------------------
// GATExtractPart: GAT encoder + attention pooling.
// Round 3: bf16 MFMA for both GEMMs; h1/hln/h2 stored bf16 (f32 accumulate).
// N=32768, E=131072 (+N self loops), B=512 graphs x 64 nodes.
// ---------------------------------------------------------------------------

#define LEAKY_SLOPE 0.2f

typedef __attribute__((ext_vector_type(8))) short bfrag8;   // 8 bf16 = 4 VGPR
typedef __attribute__((ext_vector_type(4))) float facc4;    // MFMA accumulator

__device__ inline ushort f2b(float f) {              // f32 -> bf16 bits (RNE)
    uint u = __float_as_uint(f);
    return (ushort)((u + 0x7fffu + ((u >> 16) & 1u)) >> 16);
}
__device__ inline float b2f(ushort b) {
    uint u = ((uint)b) << 16;
    return __uint_as_float(u);
}

// --- tiny precompute: we1[k][h] = sum_c We1[k,h*256+c]*ae1[h,c]; we2[k] -----
__global__ void k_pre(const float* __restrict__ We1, const float* __restrict__ ae1,
                      const float* __restrict__ We2, const float* __restrict__ ae2,
                      float* __restrict__ we1, float* __restrict__ we2) {
    int t = threadIdx.x;
    if (t < 24) {
        int k = t / 4, h = t % 4;
        float s = 0.f;
        for (int c = 0; c < 256; ++c) s += We1[k * 1024 + h * 256 + c] * ae1[h * 256 + c];
        we1[k * 4 + h] = s;
    } else if (t < 30) {
        int k = t - 24;
        float s = 0.f;
        for (int c = 0; c < 256; ++c) s += We2[k * 256 + c] * ae2[c];
        we2[k] = s;
    }
}

// --- casts into bf16 workspace ---------------------------------------------
__global__ void k_cast_x(const float* __restrict__ x, ushort* __restrict__ xb, int N) {
    int idx = blockIdx.x * blockDim.x + threadIdx.x;       // N*64
    if (idx >= N * 64) return;
    int n = idx >> 6, k = idx & 63;
    xb[idx] = (k < 55) ? f2b(x[(size_t)n * 55 + k]) : 0;
}
__global__ void k_cast_w1t(const float* __restrict__ W1, ushort* __restrict__ w1t) {
    int idx = blockIdx.x * blockDim.x + threadIdx.x;       // 1024*64
    if (idx >= 1024 * 64) return;
    int c = idx >> 6, k = idx & 63;
    w1t[idx] = (k < 55) ? f2b(W1[(size_t)k * 1024 + c]) : 0;
}
__global__ void k_cast_w2t(const float* __restrict__ W2, ushort* __restrict__ w2t) {
    int idx = blockIdx.x * blockDim.x + threadIdx.x;       // 256*1024
    if (idx >= 256 * 1024) return;
    int c = idx >> 10, k = idx & 1023;
    w2t[idx] = f2b(W2[(size_t)k * 256 + c]);
}

// --- per-dst degree + edge_attr sums (original edges only) ------------------
__global__ void k_edge_accum(const int* __restrict__ ei, const float* __restrict__ ea,
                             int* __restrict__ deg, float* __restrict__ mea, int E) {
    int e = blockIdx.x * blockDim.x + threadIdx.x;
    if (e >= E) return;
    int d = ei[E + e];
    atomicAdd(&deg[d], 1);
#pragma unroll
    for (int k = 0; k < 6; ++k) atomicAdd(&mea[d * 6 + k], ea[e * 6 + k]);
}

__global__ void k_mea_div(float* __restrict__ mea, const int* __restrict__ deg, int N) {
    int i = blockIdx.x * blockDim.x + threadIdx.x;
    if (i >= N * 6) return;
    mea[i] /= fmaxf((float)deg[i / 6], 1.f);
}

// --- exclusive scan of (deg+1) over N nodes; single block of 1024 -----------
__global__ void k_scan(const int* __restrict__ deg, int* __restrict__ off, int N) {
    __shared__ int part[1024];
    int t = threadIdx.x;
    int per = N / 1024;
    int base = t * per;
    int loc[32];
    int s = 0;
    for (int i = 0; i < per; ++i) { loc[i] = s; s += deg[base + i] + 1; }
    part[t] = s;
    __syncthreads();
    for (int o = 1; o < 1024; o <<= 1) {
        int v = (t >= o) ? part[t - o] : 0;
        __syncthreads();
        part[t] += v;
        __syncthreads();
    }
    int excl = (t == 0) ? 0 : part[t - 1];
    for (int i = 0; i < per; ++i) off[base + i] = excl + loc[i];
    if (t == 1023) off[N] = excl + s;
}

// --- CSR fill over full edge set (E originals + N self loops) ---------------
__global__ void k_fill(const int* __restrict__ ei, const int* __restrict__ coff,
                       int* __restrict__ fill, int* __restrict__ eid, int E, int Ef) {
    int e = blockIdx.x * blockDim.x + threadIdx.x;
    if (e >= Ef) return;
    int d = (e < E) ? ei[E + e] : (e - E);
    int pos = coff[d] + atomicAdd(&fill[d], 1);
    eid[pos] = e;
}

// --- bf16 MFMA GEMM: C[M,ldc] = A[M,KTOT] @ BT[Nc,KTOT]^T, all bf16 ---------
// BM=BN=128, BK=64; 256 threads = 4 waves (2x2), wave tile 64x64.
// T2 XOR-swizzle (col16 ^= row&7) on both LDS write and read.
template<int KTOT>
__global__ __launch_bounds__(256) void k_gemm_bf16(
    const ushort* __restrict__ A, const ushort* __restrict__ BT,
    ushort* __restrict__ C, int ldc) {
    __shared__ ushort As[128 * 64];
    __shared__ ushort Bs[128 * 64];
    int tid = threadIdx.x;
    int lane = tid & 63, wid = tid >> 6;
    int wr = wid >> 1, wc = wid & 1;
    int l15 = lane & 15, l4 = lane >> 4;
    int r0 = blockIdx.y * 128, c0 = blockIdx.x * 128;
    facc4 acc[4][4] = {};
    for (int kt = 0; kt < KTOT; kt += 64) {
#pragma unroll
        for (int i = 0; i < 4; ++i) {
            int ch = tid + 256 * i;
            int row = ch >> 3, col16 = ch & 7;
            int sw = col16 ^ (row & 7);
            const int4 av = *reinterpret_cast<const int4*>(A + (size_t)(r0 + row) * KTOT + kt + col16 * 8);
            *reinterpret_cast<int4*>(&As[row * 64 + sw * 8]) = av;
            const int4 bv = *reinterpret_cast<const int4*>(BT + (size_t)(c0 + row) * KTOT + kt + col16 * 8);
            *reinterpret_cast<int4*>(&Bs[row * 64 + sw * 8]) = bv;
        }
        __syncthreads();
#pragma unroll
        for (int kk = 0; kk < 2; ++kk) {
            bfrag8 af[4], bf[4];
#pragma unroll
            for (int f = 0; f < 4; ++f) {
                int arow = wr * 64 + f * 16 + l15;
                int ac = (kk * 4 + l4) ^ (arow & 7);
                af[f] = *reinterpret_cast<const bfrag8*>(&As[arow * 64 + ac * 8]);
                int brow = wc * 64 + f * 16 + l15;
                int bc = (kk * 4 + l4) ^ (brow & 7);
                bf[f] = *reinterpret_cast<const bfrag8*>(&Bs[brow * 64 + bc * 8]);
            }
#pragma unroll
            for (int fi = 0; fi < 4; ++fi)
#pragma unroll
                for (int fj = 0; fj < 4; ++fj)
                    acc[fi][fj] = __builtin_amdgcn_mfma_f32_16x16x32_bf16(
                        af[fi], bf[fj], acc[fi][fj], 0, 0, 0);
        }
        __syncthreads();
    }
#pragma unroll
    for (int fi = 0; fi < 4; ++fi)
#pragma unroll
        for (int fj = 0; fj < 4; ++fj)
#pragma unroll
            for (int i = 0; i < 4; ++i) {
                int r = r0 + wr * 64 + fi * 16 + l4 * 4 + i;
                int cc = c0 + wc * 64 + fj * 16 + l15;
                C[(size_t)r * ldc + cc] = f2b(acc[fi][fj][i]);
            }
}

// --- per-node attention scalars, layer 1 (bf16 h1) --------------------------
__global__ void k_s1(const ushort* __restrict__ h1c, const float* __restrict__ as1,
                     const float* __restrict__ ad1, float* __restrict__ ss,
                     float* __restrict__ sd, int n0) {
    int ln = blockIdx.x, tid = threadIdx.x;
    int n = n0 + ln;
    int h = tid >> 6, lane = tid & 63;
    ushort4 v4 = *reinterpret_cast<const ushort4*>(h1c + (size_t)ln * 1024 + tid * 4);
    int cb = tid * 4;
    float vs = b2f(v4.x) * as1[cb] + b2f(v4.y) * as1[cb + 1] +
               b2f(v4.z) * as1[cb + 2] + b2f(v4.w) * as1[cb + 3];
    float vd = b2f(v4.x) * ad1[cb] + b2f(v4.y) * ad1[cb + 1] +
               b2f(v4.z) * ad1[cb + 2] + b2f(v4.w) * ad1[cb + 3];
    for (int o = 32; o; o >>= 1) { vs += __shfl_down(vs, o); vd += __shfl_down(vd, o); }
    if (lane == 0) { ss[n * 4 + h] = vs; sd[n * 4 + h] = vd; }
}

// --- per-edge attention logits, layer 1 -------------------------------------
__global__ void k_al1(const int* __restrict__ ei, const float* __restrict__ ea,
                      const float* __restrict__ mea, const float* __restrict__ ss,
                      const float* __restrict__ sd, const float* __restrict__ we1,
                      float* __restrict__ al1, int E, int e0, int ECo, int n0, int NC) {
    int idx = blockIdx.x * blockDim.x + threadIdx.x;
    if (idx >= (ECo + NC) * 4) return;
    int i = idx >> 2, h = idx & 3;
    int ge, s, d;
    const float* eap;
    if (i < ECo) {
        ge = e0 + i;
        s = ei[ge];
        d = ei[E + ge];
        eap = ea + (size_t)ge * 6;
    } else {
        int n = n0 + (i - ECo);
        ge = E + n;
        s = d = n;
        eap = mea + (size_t)n * 6;
    }
    float v = ss[s * 4 + h] + sd[d * 4 + h];
#pragma unroll
    for (int k = 0; k < 6; ++k) v += eap[k] * we1[k * 4 + h];
    al1[(size_t)ge * 4 + h] = (v > 0.f) ? v : LEAKY_SLOPE * v;
}

// --- layer1 fused: softmax, aggregate, +b1, LN, ReLU -> bf16 hln ------------
__global__ void k_agg1(const ushort* __restrict__ h1c, const float* __restrict__ al1,
                       const int* __restrict__ coff, const int* __restrict__ eid,
                       const int* __restrict__ ei, const float* __restrict__ b1,
                       const float* __restrict__ g1, const float* __restrict__ be1,
                       ushort* __restrict__ hlnc, int E, int n0) {
    int ln = blockIdx.x, tid = threadIdx.x;
    int n = n0 + ln;
    int h = tid >> 6;
    int e0 = coff[n], e1 = coff[n + 1];
    float m = -1e30f;
    for (int p = e0; p < e1; ++p) m = fmaxf(m, al1[(size_t)eid[p] * 4 + h]);
    float ssum = 0.f;
    for (int p = e0; p < e1; ++p) ssum += expf(al1[(size_t)eid[p] * 4 + h] - m);
    float inv = 1.f / (ssum + 1e-16f);
    int c0 = tid * 4;
    float ax = 0.f, ay = 0.f, az = 0.f, aw = 0.f;
    for (int p = e0; p < e1; ++p) {
        int e = eid[p];
        int s = (e < E) ? ei[e] : (e - E);
        int ls = s - n0;
        float a = expf(al1[(size_t)e * 4 + h] - m) * inv;
        ushort4 hv = *reinterpret_cast<const ushort4*>(h1c + (size_t)ls * 1024 + c0);
        ax += a * b2f(hv.x); ay += a * b2f(hv.y); az += a * b2f(hv.z); aw += a * b2f(hv.w);
    }
    ax += b1[c0 + 0]; ay += b1[c0 + 1]; az += b1[c0 + 2]; aw += b1[c0 + 3];
    float lsum = ax + ay + az + aw;
    float lsq = ax * ax + ay * ay + az * az + aw * aw;
    for (int o = 32; o; o >>= 1) { lsum += __shfl_down(lsum, o); lsq += __shfl_down(lsq, o); }
    __shared__ float rs[4], rq[4];
    if ((tid & 63) == 0) { rs[tid >> 6] = lsum; rq[tid >> 6] = lsq; }
    __syncthreads();
    float mu = (rs[0] + rs[1] + rs[2] + rs[3]) * (1.f / 1024.f);
    float var = (rq[0] + rq[1] + rq[2] + rq[3]) * (1.f / 1024.f) - mu * mu;
    float rstd = rsqrtf(var + 1e-5f);
    ushort4 o4;
    o4.x = f2b(fmaxf((ax - mu) * rstd * g1[c0 + 0] + be1[c0 + 0], 0.f));
    o4.y = f2b(fmaxf((ay - mu) * rstd * g1[c0 + 1] + be1[c0 + 1], 0.f));
    o4.z = f2b(fmaxf((az - mu) * rstd * g1[c0 + 2] + be1[c0 + 2], 0.f));
    o4.w = f2b(fmaxf((aw - mu) * rstd * g1[c0 + 3] + be1[c0 + 3], 0.f));
    *reinterpret_cast<ushort4*>(hlnc + (size_t)ln * 1024 + c0) = o4;
}

// --- per-node attention scalars, layer 2 (bf16 h2) --------------------------
__global__ void k_s2(const ushort* __restrict__ h2c, const float* __restrict__ as2,
                     const float* __restrict__ ad2, float* __restrict__ ss,
                     float* __restrict__ sd, int n0) {
    int ln = blockIdx.x, lane = threadIdx.x;   // block = 64
    ushort4 v4 = *reinterpret_cast<const ushort4*>(h2c + (size_t)ln * 256 + lane * 4);
    int cb = lane * 4;
    float vs = b2f(v4.x) * as2[cb] + b2f(v4.y) * as2[cb + 1] +
               b2f(v4.z) * as2[cb + 2] + b2f(v4.w) * as2[cb + 3];
    float vd = b2f(v4.x) * ad2[cb] + b2f(v4.y) * ad2[cb + 1] +
               b2f(v4.z) * ad2[cb + 2] + b2f(v4.w) * ad2[cb + 3];
    for (int o = 32; o; o >>= 1) { vs += __shfl_down(vs, o); vd += __shfl_down(vd, o); }
    if (lane == 0) { ss[n0 + ln] = vs; sd[n0 + ln] = vd; }
}

__global__ void k_al2(const int* __restrict__ ei, const float* __restrict__ ea,
                      const float* __restrict__ mea, const float* __restrict__ ss,
                      const float* __restrict__ sd, const float* __restrict__ we2,
                      float* __restrict__ al2, int E, int e0, int ECo, int n0, int NC) {
    int i = blockIdx.x * blockDim.x + threadIdx.x;
    if (i >= ECo + NC) return;
    int ge, s, d;
    const float* eap;
    if (i < ECo) {
        ge = e0 + i;
        s = ei[ge];
        d = ei[E + ge];
        eap = ea + (size_t)ge * 6;
    } else {
        int n = n0 + (i - ECo);
        ge = E + n;
        s = d = n;
        eap = mea + (size_t)n * 6;
    }
    float v = ss[s] + sd[d];
#pragma unroll
    for (int k = 0; k < 6; ++k) v += eap[k] * we2[k];
    al2[ge] = (v > 0.f) ? v : LEAKY_SLOPE * v;
}

// --- layer2 fused: softmax, aggregate, +b2, LN -> f32 hf --------------------
__global__ void k_agg2(const ushort* __restrict__ h2c, const float* __restrict__ al2,
                       const int* __restrict__ coff, const int* __restrict__ eid,
                       const int* __restrict__ ei, const float* __restrict__ b2,
                       const float* __restrict__ g2, const float* __restrict__ be2,
                       float* __restrict__ hfc, int E, int n0) {
    int ln = blockIdx.x, tid = threadIdx.x;    // 256 threads = 256 channels
    int n = n0 + ln;
    int e0 = coff[n], e1 = coff[n + 1];
    float m = -1e30f;
    for (int p = e0; p < e1; ++p) m = fmaxf(m, al2[eid[p]]);
    float ssum = 0.f;
    for (int p = e0; p < e1; ++p) ssum += expf(al2[eid[p]] - m);
    float inv = 1.f / (ssum + 1e-16f);
    float acc = 0.f;
    for (int p = e0; p < e1; ++p) {
        int e = eid[p];
        int s = (e < E) ? ei[e] : (e - E);
        float a = expf(al2[e] - m) * inv;
        acc += a * b2f(h2c[(size_t)(s - n0) * 256 + tid]);
    }
    acc += b2[tid];
    float lsum = acc, lsq = acc * acc;
    for (int o = 32; o; o >>= 1) { lsum += __shfl_down(lsum, o); lsq += __shfl_down(lsq, o); }
    __shared__ float rs[4], rq[4];
    if ((tid & 63) == 0) { rs[tid >> 6] = lsum; rq[tid >> 6] = lsq; }
    __syncthreads();
    float mu = (rs[0] + rs[1] + rs[2] + rs[3]) * (1.f / 256.f);
    float var = (rq[0] + rq[1] + rq[2] + rq[3]) * (1.f / 256.f) - mu * mu;
    float rstd = rsqrtf(var + 1e-5f);
    hfc[(size_t)ln * 256 + tid] = (acc - mu) * rstd * g2[tid] + be2[tid];
}

// --- scores[n] = tanh(hfc[ln] @ Wa) . va ------------------------------------
__global__ void k_scores(const float* __restrict__ hfc, const float* __restrict__ Wa,
                         const float* __restrict__ va, float* __restrict__ scores,
                         int n0) {
    __shared__ float hs[16][256];
    int l0 = blockIdx.x * 16, tid = threadIdx.x;
    for (int i = tid; i < 16 * 256; i += 256)
        hs[i >> 8][i & 255] = hfc[(size_t)(l0 + (i >> 8)) * 256 + (i & 255)];
    __syncthreads();
    float acc[16] = {};
    int c = tid;
    for (int k = 0; k < 256; ++k) {
        float w = Wa[(size_t)k * 256 + c];
#pragma unroll
        for (int i = 0; i < 16; ++i) acc[i] += hs[i][k] * w;
    }
    float vc = va[c];
    __shared__ float red[4];
    for (int i = 0; i < 16; ++i) {
        float t = tanhf(acc[i]) * vc;
        for (int o = 32; o; o >>= 1) t += __shfl_down(t, o);
        if ((tid & 63) == 0) red[tid >> 6] = t;
        __syncthreads();
        if (tid == 0) scores[n0 + l0 + i] = red[0] + red[1] + red[2] + red[3];
        __syncthreads();
    }
}

// --- per-graph softmax + attention-weighted max-pool + embedding gather -----
__global__ void k_final(const float* __restrict__ hfc, const float* __restrict__ scores,
                        const int* __restrict__ food, const float* __restrict__ emb,
                        float* __restrict__ out, int B, int g0) {
    int b = g0 + blockIdx.x, tid = threadIdx.x;
    __shared__ float at[64];
    if (tid < 64) {
        float sc = scores[b * 64 + tid];
        float m = sc;
        for (int o = 32; o; o >>= 1) m = fmaxf(m, __shfl_xor(m, o));
        float ex = expf(sc - m);
        float s = ex;
        for (int o = 32; o; o >>= 1) s += __shfl_xor(s, o);
        float a = ex / (s + 1e-16f);
        at[tid] = a;
        out[(size_t)B * 512 + b * 64 + tid] = a;
    }
    __syncthreads();
    int c = tid;
    float m = -1e30f;
    int lbase = blockIdx.x * 64;
    for (int l = 0; l < 64; ++l)
        m = fmaxf(m, hfc[(size_t)(lbase + l) * 256 + c] * at[l]);
    out[(size_t)b * 256 + c] = m;
    out[(size_t)B * 256 + b * 256 + c] = emb[(size_t)food[b] * 256 + c];
}

// ---------------------------------------------------------------------------
extern "C" void kernel_launch(void* const* d_in, const int* in_sizes, int n_in,
                              void* d_out, int out_size, void* d_ws, size_t ws_size,
                              hipStream_t stream) {
    const float* x   = (const float*)d_in[0];
    const float* ea  = (const float*)d_in[1];
    const int*   ei  = (const int*)d_in[2];
    const int*   food= (const int*)d_in[4];
    const float* W1  = (const float*)d_in[5];
    const float* as1 = (const float*)d_in[6];
    const float* ad1 = (const float*)d_in[7];
    const float* We1 = (const float*)d_in[8];
    const float* ae1 = (const float*)d_in[9];
    const float* b1  = (const float*)d_in[10];
    const float* g1  = (const float*)d_in[11];
    const float* be1 = (const float*)d_in[12];
    const float* W2  = (const float*)d_in[13];
    const float* as2 = (const float*)d_in[14];
    const float* ad2 = (const float*)d_in[15];
    const float* We2 = (const float*)d_in[16];
    const float* ae2 = (const float*)d_in[17];
    const float* b2  = (const float*)d_in[18];
    const float* g2  = (const float*)d_in[19];
    const float* be2 = (const float*)d_in[20];
    const float* Wa  = (const float*)d_in[21];
    const float* va  = (const float*)d_in[22];
    const float* emb = (const float*)d_in[23];
    float* out = (float*)d_out;

    const int N  = in_sizes[0] / 55;
    const int E  = in_sizes[2] / 2;
    const int B  = in_sizes[4];
    const int Ef = E + N;
    const int LPG = N / B;      // 64
    const int EPG = E / B;      // 256

    char* w = (char*)d_ws;
    size_t off = 0;
    auto take = [&](size_t bytes) -> char* {
        char* p = w + off;
        off = (off + bytes + 255) & ~(size_t)255;
        return p;
    };
    // small full-graph buffers
    int*    deg  = (int*)take((size_t)N * 4);
    float*  mea  = (float*)take((size_t)N * 6 * 4);
    int*    coff = (int*)take((size_t)(N + 1) * 4);
    int*    fill = (int*)take((size_t)N * 4);
    int*    eid  = (int*)take((size_t)Ef * 4);
    float*  ss1  = (float*)take((size_t)N * 4 * 4);
    float*  sd1  = (float*)take((size_t)N * 4 * 4);
    float*  al1  = (float*)take((size_t)Ef * 4 * 4);
    float*  ss2  = (float*)take((size_t)N * 4);
    float*  sd2  = (float*)take((size_t)N * 4);
    float*  al2  = (float*)take((size_t)Ef * 4);
    float*  wbuf = (float*)take(256);
    float*  scores = (float*)take((size_t)N * 4);
    ushort* xb   = (ushort*)take((size_t)N * 64 * 2);
    ushort* w1t  = (ushort*)take((size_t)1024 * 64 * 2);
    ushort* w2t  = (ushort*)take((size_t)256 * 1024 * 2);
    size_t smallEnd = off;

    // chunk size: largest power-of-two graph count fitting ws (bf16 h1+hln)
    int G = B;
    while (G > 2 && smallEnd + 2ull * G * LPG * 1024 * 2 + 512 > ws_size) G >>= 1;
    ushort* h1c  = (ushort*)take((size_t)G * LPG * 1024 * 2);
    ushort* hlnc = (ushort*)take((size_t)G * LPG * 1024 * 2);
    ushort* h2c  = h1c;                                    // h1c dead after agg1
    float*  hfc  = (float*)((char*)h1c + (size_t)G * LPG * 512); // after h2c range

    hipMemsetAsync(deg, 0, (size_t)N * 4, stream);
    hipMemsetAsync(mea, 0, (size_t)N * 6 * 4, stream);
    hipMemsetAsync(fill, 0, (size_t)N * 4, stream);

    k_pre<<<1, 64, 0, stream>>>(We1, ae1, We2, ae2, wbuf, wbuf + 32);
    k_cast_x<<<(N * 64 + 255) / 256, 256, 0, stream>>>(x, xb, N);
    k_cast_w1t<<<(1024 * 64 + 255) / 256, 256, 0, stream>>>(W1, w1t);
    k_cast_w2t<<<(256 * 1024 + 255) / 256, 256, 0, stream>>>(W2, w2t);
    k_edge_accum<<<(E + 255) / 256, 256, 0, stream>>>(ei, ea, deg, mea, E);
    k_mea_div<<<(N * 6 + 255) / 256, 256, 0, stream>>>(mea, deg, N);
    k_scan<<<1, 1024, 0, stream>>>(deg, coff, N);
    k_fill<<<(Ef + 255) / 256, 256, 0, stream>>>(ei, coff, fill, eid, E, Ef);

    for (int g0 = 0; g0 < B; g0 += G) {
        int Gc  = (g0 + G <= B) ? G : (B - g0);
        int n0  = g0 * LPG;
        int e0  = g0 * EPG;
        int NC  = Gc * LPG;
        int ECo = Gc * EPG;
        // GEMM1: h1c[NC,1024] = xb[n0..,64] @ w1t^T
        k_gemm_bf16<64><<<dim3(1024 / 128, NC / 128), 256, 0, stream>>>(
            xb + (size_t)n0 * 64, w1t, h1c, 1024);
        k_s1<<<NC, 256, 0, stream>>>(h1c, as1, ad1, ss1, sd1, n0);
        k_al1<<<((ECo + NC) * 4 + 255) / 256, 256, 0, stream>>>(
            ei, ea, mea, ss1, sd1, wbuf, al1, E, e0, ECo, n0, NC);
        k_agg1<<<NC, 256, 0, stream>>>(h1c, al1, coff, eid, ei, b1, g1, be1, hlnc, E, n0);
        // GEMM2: h2c[NC,256] = hlnc[NC,1024] @ w2t^T
        k_gemm_bf16<1024><<<dim3(256 / 128, NC / 128), 256, 0, stream>>>(
            hlnc, w2t, h2c, 256);
        k_s2<<<NC, 64, 0, stream>>>(h2c, as2, ad2, ss2, sd2, n0);
        k_al2<<<(ECo + NC + 255) / 256, 256, 0, stream>>>(
            ei, ea, mea, ss2, sd2, wbuf + 32, al2, E, e0, ECo, n0, NC);
        k_agg2<<<NC, 256, 0, stream>>>(h2c, al2, coff, eid, ei, b2, g2, be2, hfc, E, n0);
        k_scores<<<NC / 16, 256, 0, stream>>>(hfc, Wa, va, scores, n0);
        k_final<<<Gc, 256, 0, stream>>>(hfc, scores, food, emb, out, B, g0);
    }
}

// Round 4
// 333.836 us; speedup vs baseline: 2.8650x; 1.6328x over previous
//
#include <hip/hip_runtime.h>
#include <cstdint>
#include <cstddef>

// ---------------------------------------------------------------------------
// GATExtractPart: GAT encoder + attention pooling.
// Round 4: per-graph fused layer kernels (LDS-staged), MFMA scores GEMM.
// N=32768, E=131072 (+N self loops), B=512 graphs x 64 nodes.
// ---------------------------------------------------------------------------

#define LEAKY_SLOPE 0.2f

typedef __attribute__((ext_vector_type(8))) short bfrag8;   // 8 bf16 = 4 VGPR
typedef __attribute__((ext_vector_type(4))) float facc4;    // MFMA accumulator

__device__ inline ushort f2b(float f) {              // f32 -> bf16 bits (RNE)
    uint u = __float_as_uint(f);
    return (ushort)((u + 0x7fffu + ((u >> 16) & 1u)) >> 16);
}
__device__ inline float b2f(ushort b) {
    uint u = ((uint)b) << 16;
    return __uint_as_float(u);
}

// --- tiny precompute: we1[k][h] = sum_c We1[k,h*256+c]*ae1[h,c]; we2[k] -----
__global__ void k_pre(const float* __restrict__ We1, const float* __restrict__ ae1,
                      const float* __restrict__ We2, const float* __restrict__ ae2,
                      float* __restrict__ we1, float* __restrict__ we2) {
    int t = threadIdx.x;
    if (t < 24) {
        int k = t / 4, h = t % 4;
        float s = 0.f;
        for (int c = 0; c < 256; ++c) s += We1[k * 1024 + h * 256 + c] * ae1[h * 256 + c];
        we1[k * 4 + h] = s;
    } else if (t < 30) {
        int k = t - 24;
        float s = 0.f;
        for (int c = 0; c < 256; ++c) s += We2[k * 256 + c] * ae2[c];
        we2[k] = s;
    }
}

// --- casts into bf16 workspace ---------------------------------------------
__global__ void k_cast_x(const float* __restrict__ x, ushort* __restrict__ xb, int N) {
    int idx = blockIdx.x * blockDim.x + threadIdx.x;       // N*64
    if (idx >= N * 64) return;
    int n = idx >> 6, k = idx & 63;
    xb[idx] = (k < 55) ? f2b(x[(size_t)n * 55 + k]) : 0;
}
__global__ void k_cast_w1t(const float* __restrict__ W1, ushort* __restrict__ w1t) {
    int idx = blockIdx.x * blockDim.x + threadIdx.x;       // 1024*64
    if (idx >= 1024 * 64) return;
    int c = idx >> 6, k = idx & 63;
    w1t[idx] = (k < 55) ? f2b(W1[(size_t)k * 1024 + c]) : 0;
}
__global__ void k_cast_w2t(const float* __restrict__ W2, ushort* __restrict__ w2t) {
    int idx = blockIdx.x * blockDim.x + threadIdx.x;       // 256*1024
    if (idx >= 256 * 1024) return;
    int c = idx >> 10, k = idx & 1023;
    w2t[idx] = f2b(W2[(size_t)k * 256 + c]);
}
__global__ void k_cast_wat(const float* __restrict__ Wa, ushort* __restrict__ wat) {
    int idx = blockIdx.x * blockDim.x + threadIdx.x;       // 256*256
    if (idx >= 256 * 256) return;
    int c = idx >> 8, k = idx & 255;
    wat[idx] = f2b(Wa[(size_t)k * 256 + c]);
}

// --- per-dst degree + edge_attr sums (original edges only) ------------------
__global__ void k_edge_accum(const int* __restrict__ ei, const float* __restrict__ ea,
                             int* __restrict__ deg, float* __restrict__ mea, int E) {
    int e = blockIdx.x * blockDim.x + threadIdx.x;
    if (e >= E) return;
    int d = ei[E + e];
    atomicAdd(&deg[d], 1);
#pragma unroll
    for (int k = 0; k < 6; ++k) atomicAdd(&mea[d * 6 + k], ea[e * 6 + k]);
}

__global__ void k_mea_div(float* __restrict__ mea, const int* __restrict__ deg, int N) {
    int i = blockIdx.x * blockDim.x + threadIdx.x;
    if (i >= N * 6) return;
    mea[i] /= fmaxf((float)deg[i / 6], 1.f);
}

// --- exclusive scan of (deg+1) over N nodes; single block of 1024 -----------
__global__ void k_scan(const int* __restrict__ deg, int* __restrict__ off, int N) {
    __shared__ int part[1024];
    int t = threadIdx.x;
    int per = N / 1024;
    int base = t * per;
    int loc[32];
    int s = 0;
    for (int i = 0; i < per; ++i) { loc[i] = s; s += deg[base + i] + 1; }
    part[t] = s;
    __syncthreads();
    for (int o = 1; o < 1024; o <<= 1) {
        int v = (t >= o) ? part[t - o] : 0;
        __syncthreads();
        part[t] += v;
        __syncthreads();
    }
    int excl = (t == 0) ? 0 : part[t - 1];
    for (int i = 0; i < per; ++i) off[base + i] = excl + loc[i];
    if (t == 1023) off[N] = excl + s;
}

// --- CSR fill over full edge set (E originals + N self loops) ---------------
__global__ void k_fill(const int* __restrict__ ei, const int* __restrict__ coff,
                       int* __restrict__ fill, int* __restrict__ eid, int E, int Ef) {
    int e = blockIdx.x * blockDim.x + threadIdx.x;
    if (e >= Ef) return;
    int d = (e < E) ? ei[E + e] : (e - E);
    int pos = coff[d] + atomicAdd(&fill[d], 1);
    eid[pos] = e;
}

// --- per-edge attr dot products for both layers -----------------------------
__global__ void k_eadot(const float* __restrict__ ea, const float* __restrict__ mea,
                        const float* __restrict__ we1, const float* __restrict__ we2,
                        float* __restrict__ eadot1, float* __restrict__ eadot2,
                        int E, int Ef) {
    int e = blockIdx.x * blockDim.x + threadIdx.x;
    if (e >= Ef) return;
    const float* eap = (e < E) ? (ea + (size_t)e * 6) : (mea + (size_t)(e - E) * 6);
    float v[4] = {};
    float v2 = 0.f;
#pragma unroll
    for (int k = 0; k < 6; ++k) {
        float a = eap[k];
#pragma unroll
        for (int h = 0; h < 4; ++h) v[h] += a * we1[k * 4 + h];
        v2 += a * we2[k];
    }
#pragma unroll
    for (int h = 0; h < 4; ++h) eadot1[(size_t)e * 4 + h] = v[h];
    eadot2[e] = v2;
}

// --- bf16 MFMA GEMM: C[M,ldc] = A[M,KTOT] @ BT[Nc,KTOT]^T, all bf16 ---------
// BM=BN=128, BK=64; 256 threads = 4 waves (2x2), wave tile 64x64.
template<int KTOT>
__global__ __launch_bounds__(256) void k_gemm_bf16(
    const ushort* __restrict__ A, const ushort* __restrict__ BT,
    ushort* __restrict__ C, int ldc) {
    __shared__ ushort As[128 * 64];
    __shared__ ushort Bs[128 * 64];
    int tid = threadIdx.x;
    int lane = tid & 63, wid = tid >> 6;
    int wr = wid >> 1, wc = wid & 1;
    int l15 = lane & 15, l4 = lane >> 4;
    int r0 = blockIdx.y * 128, c0 = blockIdx.x * 128;
    facc4 acc[4][4] = {};
    for (int kt = 0; kt < KTOT; kt += 64) {
#pragma unroll
        for (int i = 0; i < 4; ++i) {
            int ch = tid + 256 * i;
            int row = ch >> 3, col16 = ch & 7;
            int sw = col16 ^ (row & 7);
            const int4 av = *reinterpret_cast<const int4*>(A + (size_t)(r0 + row) * KTOT + kt + col16 * 8);
            *reinterpret_cast<int4*>(&As[row * 64 + sw * 8]) = av;
            const int4 bv = *reinterpret_cast<const int4*>(BT + (size_t)(c0 + row) * KTOT + kt + col16 * 8);
            *reinterpret_cast<int4*>(&Bs[row * 64 + sw * 8]) = bv;
        }
        __syncthreads();
#pragma unroll
        for (int kk = 0; kk < 2; ++kk) {
            bfrag8 af[4], bf[4];
#pragma unroll
            for (int f = 0; f < 4; ++f) {
                int arow = wr * 64 + f * 16 + l15;
                int ac = (kk * 4 + l4) ^ (arow & 7);
                af[f] = *reinterpret_cast<const bfrag8*>(&As[arow * 64 + ac * 8]);
                int brow = wc * 64 + f * 16 + l15;
                int bc = (kk * 4 + l4) ^ (brow & 7);
                bf[f] = *reinterpret_cast<const bfrag8*>(&Bs[brow * 64 + bc * 8]);
            }
#pragma unroll
            for (int fi = 0; fi < 4; ++fi)
#pragma unroll
                for (int fj = 0; fj < 4; ++fj)
                    acc[fi][fj] = __builtin_amdgcn_mfma_f32_16x16x32_bf16(
                        af[fi], bf[fj], acc[fi][fj], 0, 0, 0);
        }
        __syncthreads();
    }
#pragma unroll
    for (int fi = 0; fi < 4; ++fi)
#pragma unroll
        for (int fj = 0; fj < 4; ++fj)
#pragma unroll
            for (int i = 0; i < 4; ++i) {
                int r = r0 + wr * 64 + fi * 16 + l4 * 4 + i;
                int cc = c0 + wc * 64 + fj * 16 + l15;
                C[(size_t)r * ldc + cc] = f2b(acc[fi][fj][i]);
            }
}

// --- layer-1 fused per-graph kernel -----------------------------------------
// 1024 threads, LDS-staged 64x1024 bf16 h1 tile. One wave per node.
__global__ __launch_bounds__(1024) void k_graph1(
    const ushort* __restrict__ h1c, const int* __restrict__ coff,
    const int* __restrict__ eid, const int* __restrict__ ei,
    const float* __restrict__ eadot1,
    const float* __restrict__ as1, const float* __restrict__ ad1,
    const float* __restrict__ b1, const float* __restrict__ g1,
    const float* __restrict__ be1,
    ushort* __restrict__ hlnc, int E, int g0) {
    __shared__ ushort h1s[64 * 1024];       // 128 KB
    __shared__ float sarr[64][4], sdarr[64][4];
    __shared__ float llds[384][4];
    __shared__ int slds[384];
    int g = blockIdx.x;
    int lr0 = g * 64;
    int ng = (g0 + g) * 64;
    int tid = threadIdx.x;
    int w = tid >> 6, lane = tid & 63;
    // stage h1 graph tile (128 KB, coalesced int4)
    const int4* srcp = reinterpret_cast<const int4*>(h1c + (size_t)lr0 * 1024);
    int4* dstp = reinterpret_cast<int4*>(h1s);
    for (int i = tid; i < 8192; i += 1024) dstp[i] = srcp[i];
    __syncthreads();
    // per-node ss/sd (wave per node, 4 rounds of 16 waves)
    for (int it = 0; it < 4; ++it) {
        int ln = it * 16 + w;
        float ps[4] = {}, pd[4] = {};
#pragma unroll
        for (int j = 0; j < 8; ++j) {
            int c = j * 128 + lane * 2;
            ushort2 v = *reinterpret_cast<const ushort2*>(&h1s[ln * 1024 + c]);
            float v0 = b2f(v.x), v1 = b2f(v.y);
            int h = j >> 1;
            ps[h] += v0 * as1[c] + v1 * as1[c + 1];
            pd[h] += v0 * ad1[c] + v1 * ad1[c + 1];
        }
#pragma unroll
        for (int h = 0; h < 4; ++h)
            for (int o = 32; o; o >>= 1) {
                ps[h] += __shfl_xor(ps[h], o);
                pd[h] += __shfl_xor(pd[h], o);
            }
        if (lane == 0)
#pragma unroll
            for (int h = 0; h < 4; ++h) { sarr[ln][h] = ps[h]; sdarr[ln][h] = pd[h]; }
    }
    __syncthreads();
    // edge logits into LDS
    int pbase = coff[ng];
    int pcnt = coff[ng + 64] - pbase;
    if (pcnt > 384) pcnt = 384;
    for (int p = tid; p < pcnt; p += 1024) {
        int e = eid[pbase + p];
        int s, d;
        if (e < E) { s = ei[e]; d = ei[E + e]; }
        else { s = e - E; d = s; }
        int sl = s - ng, dl = d - ng;
        slds[p] = sl;
#pragma unroll
        for (int h = 0; h < 4; ++h) {
            float v = sarr[sl][h] + sdarr[dl][h] + eadot1[(size_t)e * 4 + h];
            llds[p][h] = (v > 0.f) ? v : LEAKY_SLOPE * v;
        }
    }
    __syncthreads();
    // per-node softmax + aggregate + bias + LN + ReLU (wave per node)
    for (int it = 0; it < 4; ++it) {
        int ln = it * 16 + w;
        int p0 = coff[ng + ln] - pbase;
        int p1 = coff[ng + ln + 1] - pbase;
        float mh[4] = {-1e30f, -1e30f, -1e30f, -1e30f};
        for (int p = p0; p < p1; ++p)
#pragma unroll
            for (int h = 0; h < 4; ++h) mh[h] = fmaxf(mh[h], llds[p][h]);
        float sh[4] = {};
        for (int p = p0; p < p1; ++p)
#pragma unroll
            for (int h = 0; h < 4; ++h) sh[h] += expf(llds[p][h] - mh[h]);
        float iv[4];
#pragma unroll
        for (int h = 0; h < 4; ++h) iv[h] = 1.f / (sh[h] + 1e-16f);
        float acc[8][2] = {};
        for (int p = p0; p < p1; ++p) {
            int sl = slds[p];
            float a[4];
#pragma unroll
            for (int h = 0; h < 4; ++h) a[h] = expf(llds[p][h] - mh[h]) * iv[h];
#pragma unroll
            for (int j = 0; j < 8; ++j) {
                int c = j * 128 + lane * 2;
                ushort2 v = *reinterpret_cast<const ushort2*>(&h1s[sl * 1024 + c]);
                float ah = a[j >> 1];
                acc[j][0] += ah * b2f(v.x);
                acc[j][1] += ah * b2f(v.y);
            }
        }
        float lsum = 0.f, lsq = 0.f;
#pragma unroll
        for (int j = 0; j < 8; ++j) {
            int c = j * 128 + lane * 2;
            acc[j][0] += b1[c]; acc[j][1] += b1[c + 1];
            lsum += acc[j][0] + acc[j][1];
            lsq += acc[j][0] * acc[j][0] + acc[j][1] * acc[j][1];
        }
        for (int o = 32; o; o >>= 1) { lsum += __shfl_xor(lsum, o); lsq += __shfl_xor(lsq, o); }
        float mu = lsum * (1.f / 1024.f);
        float var = lsq * (1.f / 1024.f) - mu * mu;
        float rstd = rsqrtf(var + 1e-5f);
#pragma unroll
        for (int j = 0; j < 8; ++j) {
            int c = j * 128 + lane * 2;
            ushort2 o2;
            o2.x = f2b(fmaxf((acc[j][0] - mu) * rstd * g1[c] + be1[c], 0.f));
            o2.y = f2b(fmaxf((acc[j][1] - mu) * rstd * g1[c + 1] + be1[c + 1], 0.f));
            *reinterpret_cast<ushort2*>(&hlnc[(size_t)(lr0 + ln) * 1024 + c]) = o2;
        }
    }
}

// --- layer-2 fused per-graph kernel (1 head, 256 ch) ------------------------
__global__ __launch_bounds__(256) void k_graph2(
    const ushort* __restrict__ h2c, const int* __restrict__ coff,
    const int* __restrict__ eid, const int* __restrict__ ei,
    const float* __restrict__ eadot2,
    const float* __restrict__ as2, const float* __restrict__ ad2,
    const float* __restrict__ b2, const float* __restrict__ g2,
    const float* __restrict__ be2,
    float* __restrict__ hfc, ushort* __restrict__ hfb, int E, int g0) {
    __shared__ ushort h2s[64 * 256];        // 32 KB
    __shared__ float sarr[64], sdarr[64];
    __shared__ float llds[384];
    __shared__ int slds[384];
    int g = blockIdx.x;
    int lr0 = g * 64;
    int ng = (g0 + g) * 64;
    int tid = threadIdx.x;
    int w = tid >> 6, lane = tid & 63;
    const int4* srcp = reinterpret_cast<const int4*>(h2c + (size_t)lr0 * 256);
    int4* dstp = reinterpret_cast<int4*>(h2s);
    for (int i = tid; i < 2048; i += 256) dstp[i] = srcp[i];
    __syncthreads();
    for (int it = 0; it < 16; ++it) {
        int ln = it * 4 + w;
        float ps = 0.f, pd = 0.f;
#pragma unroll
        for (int j = 0; j < 2; ++j) {
            int c = j * 128 + lane * 2;
            ushort2 v = *reinterpret_cast<const ushort2*>(&h2s[ln * 256 + c]);
            float v0 = b2f(v.x), v1 = b2f(v.y);
            ps += v0 * as2[c] + v1 * as2[c + 1];
            pd += v0 * ad2[c] + v1 * ad2[c + 1];
        }
        for (int o = 32; o; o >>= 1) { ps += __shfl_xor(ps, o); pd += __shfl_xor(pd, o); }
        if (lane == 0) { sarr[ln] = ps; sdarr[ln] = pd; }
    }
    __syncthreads();
    int pbase = coff[ng];
    int pcnt = coff[ng + 64] - pbase;
    if (pcnt > 384) pcnt = 384;
    for (int p = tid; p < pcnt; p += 256) {
        int e = eid[pbase + p];
        int s, d;
        if (e < E) { s = ei[e]; d = ei[E + e]; }
        else { s = e - E; d = s; }
        int sl = s - ng, dl = d - ng;
        slds[p] = sl;
        float v = sarr[sl] + sdarr[dl] + eadot2[e];
        llds[p] = (v > 0.f) ? v : LEAKY_SLOPE * v;
    }
    __syncthreads();
    for (int it = 0; it < 16; ++it) {
        int ln = it * 4 + w;
        int p0 = coff[ng + ln] - pbase;
        int p1 = coff[ng + ln + 1] - pbase;
        float mh = -1e30f;
        for (int p = p0; p < p1; ++p) mh = fmaxf(mh, llds[p]);
        float sh = 0.f;
        for (int p = p0; p < p1; ++p) sh += expf(llds[p] - mh);
        float iv = 1.f / (sh + 1e-16f);
        float acc[2][2] = {};
        for (int p = p0; p < p1; ++p) {
            int sl = slds[p];
            float a = expf(llds[p] - mh) * iv;
#pragma unroll
            for (int j = 0; j < 2; ++j) {
                int c = j * 128 + lane * 2;
                ushort2 v = *reinterpret_cast<const ushort2*>(&h2s[sl * 256 + c]);
                acc[j][0] += a * b2f(v.x);
                acc[j][1] += a * b2f(v.y);
            }
        }
        float lsum = 0.f, lsq = 0.f;
#pragma unroll
        for (int j = 0; j < 2; ++j) {
            int c = j * 128 + lane * 2;
            acc[j][0] += b2[c]; acc[j][1] += b2[c + 1];
            lsum += acc[j][0] + acc[j][1];
            lsq += acc[j][0] * acc[j][0] + acc[j][1] * acc[j][1];
        }
        for (int o = 32; o; o >>= 1) { lsum += __shfl_xor(lsum, o); lsq += __shfl_xor(lsq, o); }
        float mu = lsum * (1.f / 256.f);
        float var = lsq * (1.f / 256.f) - mu * mu;
        float rstd = rsqrtf(var + 1e-5f);
#pragma unroll
        for (int j = 0; j < 2; ++j) {
            int c = j * 128 + lane * 2;
            float o0 = (acc[j][0] - mu) * rstd * g2[c] + be2[c];
            float o1 = (acc[j][1] - mu) * rstd * g2[c + 1] + be2[c + 1];
            *reinterpret_cast<float2*>(&hfc[(size_t)(lr0 + ln) * 256 + c]) = make_float2(o0, o1);
            ushort2 ob; ob.x = f2b(o0); ob.y = f2b(o1);
            *reinterpret_cast<ushort2*>(&hfb[(size_t)(lr0 + ln) * 256 + c]) = ob;
        }
    }
}

// --- scores via MFMA: scores[n] = sum_c tanh((hfb@waT)[n,c]) * va[c] --------
__global__ __launch_bounds__(256) void k_scores_mfma(
    const ushort* __restrict__ A, const ushort* __restrict__ BT,
    const float* __restrict__ va, float* __restrict__ scores, int n0) {
    __shared__ ushort As[128 * 64];
    __shared__ ushort Bs[128 * 64];
    __shared__ float sred[2][128];
    int tid = threadIdx.x;
    int lane = tid & 63, wid = tid >> 6;
    int wr = wid >> 1, wc = wid & 1;
    int l15 = lane & 15, l4 = lane >> 4;
    int r0 = blockIdx.x * 128;
    float rowpart[4][4] = {};
    for (int cb = 0; cb < 2; ++cb) {
        facc4 acc[4][4] = {};
        for (int kt = 0; kt < 256; kt += 64) {
#pragma unroll
            for (int i = 0; i < 4; ++i) {
                int ch = tid + 256 * i;
                int row = ch >> 3, col16 = ch & 7;
                int sw = col16 ^ (row & 7);
                *reinterpret_cast<int4*>(&As[row * 64 + sw * 8]) =
                    *reinterpret_cast<const int4*>(A + (size_t)(r0 + row) * 256 + kt + col16 * 8);
                *reinterpret_cast<int4*>(&Bs[row * 64 + sw * 8]) =
                    *reinterpret_cast<const int4*>(BT + (size_t)(cb * 128 + row) * 256 + kt + col16 * 8);
            }
            __syncthreads();
#pragma unroll
            for (int kk = 0; kk < 2; ++kk) {
                bfrag8 af[4], bf[4];
#pragma unroll
                for (int f = 0; f < 4; ++f) {
                    int arow = wr * 64 + f * 16 + l15;
                    int ac = (kk * 4 + l4) ^ (arow & 7);
                    af[f] = *reinterpret_cast<const bfrag8*>(&As[arow * 64 + ac * 8]);
                    int brow = wc * 64 + f * 16 + l15;
                    int bc = (kk * 4 + l4) ^ (brow & 7);
                    bf[f] = *reinterpret_cast<const bfrag8*>(&Bs[brow * 64 + bc * 8]);
                }
#pragma unroll
                for (int fi = 0; fi < 4; ++fi)
#pragma unroll
                    for (int fj = 0; fj < 4; ++fj)
                        acc[fi][fj] = __builtin_amdgcn_mfma_f32_16x16x32_bf16(
                            af[fi], bf[fj], acc[fi][fj], 0, 0, 0);
            }
            __syncthreads();
        }
        // fused epilogue: tanh * va, accumulate per-row partials
#pragma unroll
        for (int fj = 0; fj < 4; ++fj) {
            float vac = va[cb * 128 + wc * 64 + fj * 16 + l15];
#pragma unroll
            for (int fi = 0; fi < 4; ++fi)
#pragma unroll
                for (int i = 0; i < 4; ++i)
                    rowpart[fi][i] += tanhf(acc[fi][fj][i]) * vac;
        }
    }
#pragma unroll
    for (int fi = 0; fi < 4; ++fi)
#pragma unroll
        for (int i = 0; i < 4; ++i) {
            float v = rowpart[fi][i];
            v += __shfl_xor(v, 1); v += __shfl_xor(v, 2);
            v += __shfl_xor(v, 4); v += __shfl_xor(v, 8);
            rowpart[fi][i] = v;
        }
    if (l15 == 0)
#pragma unroll
        for (int fi = 0; fi < 4; ++fi)
#pragma unroll
            for (int i = 0; i < 4; ++i)
                sred[wc][wr * 64 + fi * 16 + l4 * 4 + i] = rowpart[fi][i];
    __syncthreads();
    if (tid < 128) scores[n0 + r0 + tid] = sred[0][tid] + sred[1][tid];
}

// --- per-graph softmax + attention-weighted max-pool + embedding gather -----
__global__ void k_final(const float* __restrict__ hfc, const float* __restrict__ scores,
                        const int* __restrict__ food, const float* __restrict__ emb,
                        float* __restrict__ out, int B, int g0) {
    int b = g0 + blockIdx.x, tid = threadIdx.x;
    __shared__ float at[64];
    if (tid < 64) {
        float sc = scores[b * 64 + tid];
        float m = sc;
        for (int o = 32; o; o >>= 1) m = fmaxf(m, __shfl_xor(m, o));
        float ex = expf(sc - m);
        float s = ex;
        for (int o = 32; o; o >>= 1) s += __shfl_xor(s, o);
        float a = ex / (s + 1e-16f);
        at[tid] = a;
        out[(size_t)B * 512 + b * 64 + tid] = a;
    }
    __syncthreads();
    int c = tid;
    float m = -1e30f;
    int lbase = blockIdx.x * 64;
    for (int l = 0; l < 64; ++l)
        m = fmaxf(m, hfc[(size_t)(lbase + l) * 256 + c] * at[l]);
    out[(size_t)b * 256 + c] = m;
    out[(size_t)B * 256 + b * 256 + c] = emb[(size_t)food[b] * 256 + c];
}

// ---------------------------------------------------------------------------
extern "C" void kernel_launch(void* const* d_in, const int* in_sizes, int n_in,
                              void* d_out, int out_size, void* d_ws, size_t ws_size,
                              hipStream_t stream) {
    const float* x   = (const float*)d_in[0];
    const float* ea  = (const float*)d_in[1];
    const int*   ei  = (const int*)d_in[2];
    const int*   food= (const int*)d_in[4];
    const float* W1  = (const float*)d_in[5];
    const float* as1 = (const float*)d_in[6];
    const float* ad1 = (const float*)d_in[7];
    const float* We1 = (const float*)d_in[8];
    const float* ae1 = (const float*)d_in[9];
    const float* b1  = (const float*)d_in[10];
    const float* g1  = (const float*)d_in[11];
    const float* be1 = (const float*)d_in[12];
    const float* W2  = (const float*)d_in[13];
    const float* as2 = (const float*)d_in[14];
    const float* ad2 = (const float*)d_in[15];
    const float* We2 = (const float*)d_in[16];
    const float* ae2 = (const float*)d_in[17];
    const float* b2  = (const float*)d_in[18];
    const float* g2  = (const float*)d_in[19];
    const float* be2 = (const float*)d_in[20];
    const float* Wa  = (const float*)d_in[21];
    const float* va  = (const float*)d_in[22];
    const float* emb = (const float*)d_in[23];
    float* out = (float*)d_out;

    const int N  = in_sizes[0] / 55;
    const int E  = in_sizes[2] / 2;
    const int B  = in_sizes[4];
    const int Ef = E + N;
    const int LPG = N / B;      // 64
    const int EPG = E / B;      // 256
    (void)EPG;

    char* w = (char*)d_ws;
    size_t off = 0;
    auto take = [&](size_t bytes) -> char* {
        char* p = w + off;
        off = (off + bytes + 255) & ~(size_t)255;
        return p;
    };
    // full-graph small buffers
    int*    deg  = (int*)take((size_t)N * 4);
    float*  mea  = (float*)take((size_t)N * 6 * 4);
    int*    coff = (int*)take((size_t)(N + 1) * 4);
    int*    fill = (int*)take((size_t)N * 4);
    int*    eid  = (int*)take((size_t)Ef * 4);
    float*  ead1 = (float*)take((size_t)Ef * 4 * 4);
    float*  ead2 = (float*)take((size_t)Ef * 4);
    float*  wbuf = (float*)take(256);
    float*  scores = (float*)take((size_t)N * 4);
    ushort* xb   = (ushort*)take((size_t)N * 64 * 2);
    ushort* w1t  = (ushort*)take((size_t)1024 * 64 * 2);
    ushort* w2t  = (ushort*)take((size_t)256 * 1024 * 2);
    ushort* wat  = (ushort*)take((size_t)256 * 256 * 2);
    size_t smallEnd = off;

    // chunk: largest power-of-two graph count whose bf16 h1+hln fit ws
    int G = B;
    while (G > 2 && smallEnd + 2ull * G * LPG * 1024 * 2 + 512 > ws_size) G >>= 1;
    ushort* h1c  = (ushort*)take((size_t)G * LPG * 1024 * 2);
    ushort* hlnc = (ushort*)take((size_t)G * LPG * 1024 * 2);
    // carve h2c / hfc / hfb inside the (dead-after-graph1) h1c region:
    // h2c: G*64*256*2 = G*32768 B; hfc: G*65536 B; hfb: G*32768 B; total = h1c size.
    ushort* h2c = h1c;
    float*  hfc = (float*)((char*)h1c + (size_t)G * 32768);
    ushort* hfb = (ushort*)((char*)h1c + (size_t)G * 98304);

    hipMemsetAsync(deg, 0, (size_t)N * 4, stream);
    hipMemsetAsync(mea, 0, (size_t)N * 6 * 4, stream);
    hipMemsetAsync(fill, 0, (size_t)N * 4, stream);

    k_pre<<<1, 64, 0, stream>>>(We1, ae1, We2, ae2, wbuf, wbuf + 32);
    k_cast_x<<<(N * 64 + 255) / 256, 256, 0, stream>>>(x, xb, N);
    k_cast_w1t<<<(1024 * 64 + 255) / 256, 256, 0, stream>>>(W1, w1t);
    k_cast_w2t<<<(256 * 1024 + 255) / 256, 256, 0, stream>>>(W2, w2t);
    k_cast_wat<<<(256 * 256 + 255) / 256, 256, 0, stream>>>(Wa, wat);
    k_edge_accum<<<(E + 255) / 256, 256, 0, stream>>>(ei, ea, deg, mea, E);
    k_mea_div<<<(N * 6 + 255) / 256, 256, 0, stream>>>(mea, deg, N);
    k_scan<<<1, 1024, 0, stream>>>(deg, coff, N);
    k_fill<<<(Ef + 255) / 256, 256, 0, stream>>>(ei, coff, fill, eid, E, Ef);
    k_eadot<<<(Ef + 255) / 256, 256, 0, stream>>>(ea, mea, wbuf, wbuf + 32, ead1, ead2, E, Ef);

    for (int g0 = 0; g0 < B; g0 += G) {
        int Gc = (g0 + G <= B) ? G : (B - g0);
        int n0 = g0 * LPG;
        int NC = Gc * LPG;
        // GEMM1: h1c[NC,1024] = xb[n0..,64] @ w1t^T
        k_gemm_bf16<64><<<dim3(1024 / 128, NC / 128), 256, 0, stream>>>(
            xb + (size_t)n0 * 64, w1t, h1c, 1024);
        // fused layer 1 (per graph)
        k_graph1<<<Gc, 1024, 0, stream>>>(h1c, coff, eid, ei, ead1,
                                          as1, ad1, b1, g1, be1, hlnc, E, g0);
        // GEMM2: h2c[NC,256] = hlnc[NC,1024] @ w2t^T
        k_gemm_bf16<1024><<<dim3(256 / 128, NC / 128), 256, 0, stream>>>(
            hlnc, w2t, h2c, 256);
        // fused layer 2 (per graph)
        k_graph2<<<Gc, 256, 0, stream>>>(h2c, coff, eid, ei, ead2,
                                         as2, ad2, b2, g2, be2, hfc, hfb, E, g0);
        // scores via MFMA + fused tanh/va epilogue
        k_scores_mfma<<<NC / 128, 256, 0, stream>>>(hfb, wat, va, scores, n0);
        // pooling + outputs
        k_final<<<Gc, 256, 0, stream>>>(hfc, scores, food, emb, out, B, g0);
    }
}